// Round 4
// baseline (130.855 us; speedup 1.0000x reference)
//
#include <hip/hip_runtime.h>

// SigScale: out[b, off_k + n] = x[b, off_k + n] * prod_{j} y[b, digit_j(n)]
// B=256, D=8, M=6, siglen = 299592 floats/row. Memory-bound (~614 MB HBM).
// Row byte pitch 1198368 ≡ 32 (mod 128) -> per-row quad phase s = (-2b)&7
// makes bulk float4 wave accesses 128B-aligned.
// R4: removed nontemporal hints (match the 6.29 TB/s copy ubench exactly),
//     batch 8 quads/thread (predicted-neutral, for load-burst grouping).

#define SIGLEN 299592
#define NQ     74898   // SIGLEN / 4

typedef float f4 __attribute__((ext_vector_type(4)));

__device__ __forceinline__ float quad_g(int q,
                                        const float* __restrict__ f1,
                                        const float* __restrict__ f2,
                                        const float* __restrict__ f3,
                                        int& nout) {
    const int pos = q << 2;   // float index within the row
    int n; float g;
    if (pos >= 37448) {            // level 6: prefix p = n>>3 has 15 bits
        n = pos - 37448; const int p = n >> 3; g = f3[p >> 6] * f2[p & 63];
    } else if (pos >= 4680) {      // level 5: prefix 12 bits
        n = pos - 4680;  const int p = n >> 3; g = f3[p >> 3] * f1[p & 7];
    } else if (pos >= 584) {       // level 4: prefix 9 bits
        n = pos - 584;   g = f3[n >> 3];
    } else if (pos >= 72) {        // level 3
        n = pos - 72;    g = f2[n >> 3];
    } else if (pos >= 8) {         // level 2
        n = pos - 8;     g = f1[n >> 3];
    } else {                       // level 1
        n = pos;         g = 1.0f;
    }
    nout = n;
    return g;
}

__global__ __launch_bounds__(256) void sigscale_kernel(
    const float* __restrict__ x,
    const float* __restrict__ y,
    float* __restrict__ out)
{
    __shared__ __align__(16) float f1[8];   // y
    __shared__ float f2[64];                // y⊗y
    __shared__ float f3[512];               // y⊗y⊗y

    const int b   = blockIdx.y;
    const int tid = threadIdx.x;

    if (tid < 8) f1[tid] = y[b * 8 + tid];
    __syncthreads();
    if (tid < 64) f2[tid] = f1[tid >> 3] * f1[tid & 7];
    __syncthreads();
    for (int i = tid; i < 512; i += 256) f3[i] = f2[i >> 3] * f1[i & 7];
    __syncthreads();

    // low-digit factors in registers (no LDS read needed for the last digit)
    const f4 ylo = *reinterpret_cast<const f4*>(&f1[0]);
    const f4 yhi = *reinterpret_cast<const f4*>(&f1[4]);

    const f4* __restrict__ xr   = reinterpret_cast<const f4*>(x + (size_t)b * SIGLEN);
    f4* __restrict__       orow = reinterpret_cast<f4*>(out + (size_t)b * SIGLEN);

    // phase shift so bulk accesses are 128B-aligned: (32*b + 16*s) % 128 == 0
    const int s = (-(b << 1)) & 7;

    // head quads [0, s) — levels 1..2 only, handled by block x==0
    if (blockIdx.x == 0 && tid < s) {
        const int q = tid;
        int n; const float g = quad_g(q, f1, f2, f3, n);
        const f4 yl = (n & 4) ? yhi : ylo;
        orow[q] = xr[q] * g * yl;
    }

    constexpr int STRIDE = 2048;   // 8 blocks x 256 threads per row
    int q = s + blockIdx.x * 256 + tid;

    // main loop: 8 batched float4 loads (128B/lane in flight), then 8 stores
    for (; q < NQ - 7 * STRIDE; q += 8 * STRIDE) {
        f4 v[8]; float g[8]; int n[8];
        #pragma unroll
        for (int j = 0; j < 8; ++j) v[j] = xr[q + j * STRIDE];
        #pragma unroll
        for (int j = 0; j < 8; ++j) g[j] = quad_g(q + j * STRIDE, f1, f2, f3, n[j]);
        #pragma unroll
        for (int j = 0; j < 8; ++j) {
            const f4 a = (n[j] & 4) ? yhi : ylo;
            orow[q + j * STRIDE] = v[j] * (g[j] * a);
        }
    }

    // tail singles
    for (; q < NQ; q += STRIDE) {
        int n; const float g = quad_g(q, f1, f2, f3, n);
        const f4 yl = (n & 4) ? yhi : ylo;
        orow[q] = xr[q] * (g * yl);
    }
}

extern "C" void kernel_launch(void* const* d_in, const int* in_sizes, int n_in,
                              void* d_out, int out_size, void* d_ws, size_t ws_size,
                              hipStream_t stream) {
    const float* x = (const float*)d_in[0];
    const float* y = (const float*)d_in[1];
    float* out = (float*)d_out;

    dim3 grid(8, 256);   // 2048 blocks = 8 blocks/CU, exactly resident
    sigscale_kernel<<<grid, 256, 0, stream>>>(x, y, out);
}

// Round 5
// 123.921 us; speedup vs baseline: 1.0560x; 1.0560x over previous
//
#include <hip/hip_runtime.h>

// SigScale: out[b, off_k + n] = x[b, off_k + n] * prod_{j} y[b, digit_j(n)]
// B=256, D=8, M=6, siglen = 299592 floats/row. Memory-bound (~614 MB HBM).
// Row byte pitch 1198368 ≡ 32 (mod 128) -> per-row quad phase s = (-2b)&7
// makes bulk float4 wave accesses 128B-aligned.
// R5: R3 config (batch 4 + NT load/store + grid 8x256) restored;
//     + __launch_bounds__(256,8) pins <=64 VGPR (8 waves/SIMD, 8 blocks/CU resident);
//     + 2-deep pipeline: issue next batch's NT loads BEFORE current batch's stores.

#define SIGLEN 299592
#define NQ     74898   // SIGLEN / 4

typedef float f4 __attribute__((ext_vector_type(4)));

__device__ __forceinline__ float quad_g(int q,
                                        const float* __restrict__ f1,
                                        const float* __restrict__ f2,
                                        const float* __restrict__ f3,
                                        int& nout) {
    const int pos = q << 2;   // float index within the row
    int n; float g;
    if (pos >= 37448) {            // level 6: prefix p = n>>3 has 15 bits
        n = pos - 37448; const int p = n >> 3; g = f3[p >> 6] * f2[p & 63];
    } else if (pos >= 4680) {      // level 5: prefix 12 bits
        n = pos - 4680;  const int p = n >> 3; g = f3[p >> 3] * f1[p & 7];
    } else if (pos >= 584) {       // level 4: prefix 9 bits
        n = pos - 584;   g = f3[n >> 3];
    } else if (pos >= 72) {        // level 3
        n = pos - 72;    g = f2[n >> 3];
    } else if (pos >= 8) {         // level 2
        n = pos - 8;     g = f1[n >> 3];
    } else {                       // level 1
        n = pos;         g = 1.0f;
    }
    nout = n;
    return g;
}

__global__ __launch_bounds__(256, 8) void sigscale_kernel(
    const float* __restrict__ x,
    const float* __restrict__ y,
    float* __restrict__ out)
{
    __shared__ __align__(16) float f1[8];   // y
    __shared__ float f2[64];                // y⊗y
    __shared__ float f3[512];               // y⊗y⊗y

    const int b   = blockIdx.y;
    const int tid = threadIdx.x;

    if (tid < 8) f1[tid] = y[b * 8 + tid];
    __syncthreads();
    if (tid < 64) f2[tid] = f1[tid >> 3] * f1[tid & 7];
    __syncthreads();
    for (int i = tid; i < 512; i += 256) f3[i] = f2[i >> 3] * f1[i & 7];
    __syncthreads();

    // low-digit factors in registers (no LDS read needed for the last digit)
    const f4 ylo = *reinterpret_cast<const f4*>(&f1[0]);
    const f4 yhi = *reinterpret_cast<const f4*>(&f1[4]);

    const f4* __restrict__ xr   = reinterpret_cast<const f4*>(x + (size_t)b * SIGLEN);
    f4* __restrict__       orow = reinterpret_cast<f4*>(out + (size_t)b * SIGLEN);

    // phase shift so bulk accesses are 128B-aligned: (32*b + 16*s) % 128 == 0
    const int s = (-(b << 1)) & 7;

    // head quads [0, s) — levels 1..2 only, handled by block x==0
    if (blockIdx.x == 0 && tid < s) {
        const int q = tid;
        int n; const float g = quad_g(q, f1, f2, f3, n);
        const f4 yl = (n & 4) ? yhi : ylo;
        orow[q] = xr[q] * (g * yl);
    }

    constexpr int STRIDE = 2048;          // 8 blocks x 256 threads per row
    constexpr int BATCH  = 4;
    constexpr int SPAN   = BATCH * STRIDE;

    int q = s + blockIdx.x * 256 + tid;

    // 2-deep pipeline: loads for batch i+1 issue before stores of batch i.
    f4 v[BATCH];
    bool have = (q + (BATCH - 1) * STRIDE) < NQ;
    if (have) {
        #pragma unroll
        for (int j = 0; j < BATCH; ++j)
            v[j] = __builtin_nontemporal_load(&xr[q + j * STRIDE]);
    }
    while (have) {
        const int qn = q + SPAN;
        const bool have_next = (qn + (BATCH - 1) * STRIDE) < NQ;
        f4 w[BATCH];
        if (have_next) {
            #pragma unroll
            for (int j = 0; j < BATCH; ++j)
                w[j] = __builtin_nontemporal_load(&xr[qn + j * STRIDE]);
        }
        #pragma unroll
        for (int j = 0; j < BATCH; ++j) {
            int n; const float g = quad_g(q + j * STRIDE, f1, f2, f3, n);
            const f4 a = (n & 4) ? yhi : ylo;
            __builtin_nontemporal_store(v[j] * (g * a), &orow[q + j * STRIDE]);
        }
        if (have_next) {
            #pragma unroll
            for (int j = 0; j < BATCH; ++j) v[j] = w[j];
        }
        q = qn;
        have = have_next;
    }

    // tail singles
    for (; q < NQ; q += STRIDE) {
        int n; const float g = quad_g(q, f1, f2, f3, n);
        const f4 yl = (n & 4) ? yhi : ylo;
        const f4 t = __builtin_nontemporal_load(&xr[q]);
        __builtin_nontemporal_store(t * (g * yl), &orow[q]);
    }
}

extern "C" void kernel_launch(void* const* d_in, const int* in_sizes, int n_in,
                              void* d_out, int out_size, void* d_ws, size_t ws_size,
                              hipStream_t stream) {
    const float* x = (const float*)d_in[0];
    const float* y = (const float*)d_in[1];
    float* out = (float*)d_out;

    dim3 grid(8, 256);   // 2048 blocks = 8 blocks/CU, exactly resident
    sigscale_kernel<<<grid, 256, 0, stream>>>(x, y, out);
}